// Round 1
// baseline (370.351 us; speedup 1.0000x reference)
//
#include <hip/hip_runtime.h>

typedef unsigned short u16;
typedef __bf16 bf16x8 __attribute__((ext_vector_type(8)));
typedef float f32x4 __attribute__((ext_vector_type(4)));

#define B_ 4
#define T_ 4096
#define D_ 1024
#define H_ 1024
#define M_ 16384   // B*T
#define N_ 2048    // 2H
#define K_ 1024
#define CHANS 4096 // B*H
#define CHUNKS 32
#define CLEN 128   // T / CHUNKS

// fp32 -> bf16 round-to-nearest-even via bit trick (no __bf16 scalar conv dependence)
__device__ __forceinline__ u16 f2b(float f) {
    unsigned u = __float_as_uint(f);
    unsigned r = (u + 0x7FFFu + ((u >> 16) & 1u)) >> 16;
    return (u16)r;
}

#define GLDS16(gp, lp)                                                         \
    __builtin_amdgcn_global_load_lds(                                          \
        (__attribute__((address_space(1))) void*)(gp),                         \
        (__attribute__((address_space(3))) void*)(lp), 16, 0, 0)

// ---------------- convert x: fp32 -> bf16, 8 elems/thread ----------------
__global__ __launch_bounds__(256) void cvt_x(const float* __restrict__ in,
                                             u16* __restrict__ out, int n8) {
    int i = blockIdx.x * 256 + threadIdx.x;
    int stride = gridDim.x * 256;
    for (; i < n8; i += stride) {
        const float4* p = (const float4*)(in + (size_t)i * 8);
        float4 v0 = p[0], v1 = p[1];
        u16 o[8];
        o[0] = f2b(v0.x); o[1] = f2b(v0.y); o[2] = f2b(v0.z); o[3] = f2b(v0.w);
        o[4] = f2b(v1.x); o[5] = f2b(v1.y); o[6] = f2b(v1.z); o[7] = f2b(v1.w);
        *(uint4*)(out + (size_t)i * 8) = *(const uint4*)o;
    }
}

// ---------------- transpose + convert W: [K][N] f32 -> [N][K] bf16 ----------------
__global__ __launch_bounds__(256) void tr_w(const float* __restrict__ W,
                                            u16* __restrict__ Wt) {
    __shared__ float tile[32][33];
    int kt = blockIdx.x * 32;
    int nt = blockIdx.y * 32;
    int tx = threadIdx.x & 31;
    int ty = threadIdx.x >> 5; // 0..7
#pragma unroll
    for (int i = 0; i < 4; ++i)
        tile[ty + i * 8][tx] = W[(size_t)(kt + ty + i * 8) * N_ + nt + tx];
    __syncthreads();
#pragma unroll
    for (int i = 0; i < 4; ++i)
        Wt[(size_t)(nt + ty + i * 8) * K_ + kt + tx] = f2b(tile[tx][ty + i * 8]);
}

// ---------------- bf16 MFMA GEMM, 128x128 tile, BK=32, m97 structure ----------------
// A: [M][K] bf16 row-major; Bt: [N][K] bf16 row-major (= W^T); out: [M][N] f32 = A@W + bias
__global__ __launch_bounds__(256) void gemm_bias(const u16* __restrict__ A,
                                                 const u16* __restrict__ Bt,
                                                 const float* __restrict__ bias,
                                                 float* __restrict__ C) {
    __shared__ u16 As[128][32];
    __shared__ u16 Bs[128][32];

    const int tid = threadIdx.x;
    const int wave = tid >> 6;
    const int lane = tid & 63;
    const int row0 = blockIdx.x * 128;
    const int col0 = blockIdx.y * 128;

    // staging map: call c, wave w, lane l -> LDS row c*64 + w*16 + (l>>2), k-chunk (l&3)*8
    const int sr = wave * 16 + (lane >> 2);
    const int sk = (lane & 3) * 8;
    const u16* Ap0 = A + (size_t)(row0 + sr) * K_ + sk;
    const u16* Ap1 = A + (size_t)(row0 + 64 + sr) * K_ + sk;
    const u16* Bp0 = Bt + (size_t)(col0 + sr) * K_ + sk;
    const u16* Bp1 = Bt + (size_t)(col0 + 64 + sr) * K_ + sk;
    u16* AsD0 = &As[sr][sk];
    u16* AsD1 = &As[64 + sr][sk];
    u16* BsD0 = &Bs[sr][sk];
    u16* BsD1 = &Bs[64 + sr][sk];

    const int wr = (wave >> 1) * 64; // wave quadrant
    const int wc = (wave & 1) * 64;
    const int fr = lane & 15;
    const int fk = (lane >> 4) * 8;

    f32x4 acc[4][4];
#pragma unroll
    for (int m = 0; m < 4; ++m)
#pragma unroll
        for (int n = 0; n < 4; ++n) acc[m][n] = (f32x4){0.f, 0.f, 0.f, 0.f};

    for (int k0 = 0; k0 < K_; k0 += 32) {
        GLDS16(Ap0 + k0, AsD0);
        GLDS16(Ap1 + k0, AsD1);
        GLDS16(Bp0 + k0, BsD0);
        GLDS16(Bp1 + k0, BsD1);
        __syncthreads(); // compiler emits vmcnt(0) drain before barrier

        bf16x8 af[4], bfr[4];
#pragma unroll
        for (int m = 0; m < 4; ++m)
            af[m] = *(const bf16x8*)&As[wr + m * 16 + fr][fk];
#pragma unroll
        for (int n = 0; n < 4; ++n)
            bfr[n] = *(const bf16x8*)&Bs[wc + n * 16 + fr][fk];
#pragma unroll
        for (int m = 0; m < 4; ++m)
#pragma unroll
            for (int n = 0; n < 4; ++n)
                acc[m][n] = __builtin_amdgcn_mfma_f32_16x16x32_bf16(
                    af[m], bfr[n], acc[m][n], 0, 0, 0);
        __syncthreads();
    }

    // epilogue: C/D layout col=lane&15, row=(lane>>4)*4+j  [guide m89-verified]
    const int orow = (lane >> 4) * 4;
    const int ocol = lane & 15;
#pragma unroll
    for (int n = 0; n < 4; ++n) {
        int col = col0 + wc + n * 16 + ocol;
        float bv = bias[col];
#pragma unroll
        for (int m = 0; m < 4; ++m) {
            size_t r = (size_t)(row0 + wr + m * 16 + orow);
#pragma unroll
            for (int j = 0; j < 4; ++j)
                C[(r + j) * N_ + col] = acc[m][n][j] + bv;
        }
    }
}

// ---------------- scan pass A: per-(channel,chunk) affine aggregate ----------------
__device__ __forceinline__ float sigm(float x) {
    return 1.f / (1.f + __expf(-x));
}

__global__ __launch_bounds__(256) void scan_passA(const float* __restrict__ proj,
                                                  float* __restrict__ Aagg,
                                                  float* __restrict__ Uagg) {
    int i = blockIdx.x * 256 + threadIdx.x; // [0, CHANS*CHUNKS)
    int chan = i & (CHANS - 1);
    int chunk = i >> 12;
    int b = chan >> 10, h = chan & 1023;
    size_t base = ((size_t)b * T_ + (size_t)chunk * CLEN) * N_ + h;
    float a = 1.f, u = 0.f;
#pragma unroll 4
    for (int t = 0; t < CLEN; ++t) {
        float pg = proj[base];
        float pv = proj[base + H_];
        float g = sigm(pg);
        float in = (1.f - g) * pv;
        u = u * g + in;
        a *= g;
        base += N_;
    }
    Aagg[i] = a;
    Uagg[i] = u;
}

// ---------------- scan pass B: scan chunk aggregates, emit chunk h0 + state ----------------
__global__ __launch_bounds__(256) void scan_passB(const float* __restrict__ Aagg,
                                                  const float* __restrict__ Uagg,
                                                  const float* __restrict__ state_in,
                                                  float* __restrict__ chunkH0,
                                                  float* __restrict__ state_out) {
    int chan = blockIdx.x * 256 + threadIdx.x; // [0, CHANS)
    float h = state_in[chan];
#pragma unroll
    for (int c = 0; c < CHUNKS; ++c) {
        chunkH0[c * CHANS + chan] = h;
        h = Aagg[c * CHANS + chan] * h + Uagg[c * CHANS + chan];
    }
    state_out[chan] = h; // h_{T-1}
}

// ---------------- scan pass C: replay chunk, write h (bf16 for layer0, f32 for layer1) ----
template <int OUT_BF16>
__global__ __launch_bounds__(256) void scan_passC(const float* __restrict__ proj,
                                                  const float* __restrict__ chunkH0,
                                                  void* __restrict__ outp) {
    int i = blockIdx.x * 256 + threadIdx.x;
    int chan = i & (CHANS - 1);
    int chunk = i >> 12;
    int b = chan >> 10, h = chan & 1023;
    size_t base = ((size_t)b * T_ + (size_t)chunk * CLEN) * N_ + h;
    size_t obase = ((size_t)b * T_ + (size_t)chunk * CLEN) * H_ + h;
    float hh = chunkH0[chunk * CHANS + chan];
#pragma unroll 4
    for (int t = 0; t < CLEN; ++t) {
        float pg = proj[base];
        float pv = proj[base + H_];
        float g = sigm(pg);
        float in = (1.f - g) * pv;
        hh = g * hh + in;
        if (OUT_BF16)
            ((u16*)outp)[obase] = f2b(hh);
        else
            ((float*)outp)[obase] = hh;
        base += N_;
        obase += H_;
    }
}

extern "C" void kernel_launch(void* const* d_in, const int* in_sizes, int n_in,
                              void* d_out, int out_size, void* d_ws, size_t ws_size,
                              hipStream_t stream) {
    const float* x = (const float*)d_in[0];
    const float* W0 = (const float*)d_in[1];
    const float* b0 = (const float*)d_in[2];
    const float* W1 = (const float*)d_in[3];
    const float* b1 = (const float*)d_in[4];
    const float* state = (const float*)d_in[5];
    float* out = (float*)d_out;

    char* ws = (char*)d_ws;
    u16* xb = (u16*)ws;                                   // 33,554,432 B
    u16* h1b = (u16*)(ws + 33554432);                     // 33,554,432 B
    u16* Wt = (u16*)(ws + 67108864);                      // 8,388,608 B (2 layers)
    float* proj = (float*)(ws + 75497472);                // 134,217,728 B
    float* Aagg = (float*)(ws + 209715200);               // 524,288 B
    float* Uagg = (float*)(ws + 210239488);               // 524,288 B
    float* cH0 = (float*)(ws + 210763776);                // 524,288 B

    cvt_x<<<2048, 256, 0, stream>>>(x, xb, M_ * K_ / 8);
    tr_w<<<dim3(32, 64), 256, 0, stream>>>(W0, Wt);
    tr_w<<<dim3(32, 64), 256, 0, stream>>>(W1, Wt + (size_t)N_ * K_);

    for (int l = 0; l < 2; ++l) {
        const u16* Aop = l ? h1b : xb;
        const float* bias = l ? b1 : b0;
        gemm_bias<<<dim3(M_ / 128, N_ / 128), 256, 0, stream>>>(
            Aop, Wt + (size_t)l * N_ * K_, bias, proj);
        scan_passA<<<(CHANS * CHUNKS) / 256, 256, 0, stream>>>(proj, Aagg, Uagg);
        scan_passB<<<CHANS / 256, 256, 0, stream>>>(
            Aagg, Uagg, state + (size_t)l * CHANS, cH0,
            out + (size_t)M_ * H_ + (size_t)l * CHANS);
        if (l == 0)
            scan_passC<1><<<(CHANS * CHUNKS) / 256, 256, 0, stream>>>(proj, cH0, h1b);
        else
            scan_passC<0><<<(CHANS * CHUNKS) / 256, 256, 0, stream>>>(proj, cH0, out);
    }
}

// Round 2
// 280.819 us; speedup vs baseline: 1.3188x; 1.3188x over previous
//
#include <hip/hip_runtime.h>

typedef unsigned short u16;
typedef __bf16 bf16x8 __attribute__((ext_vector_type(8)));
typedef float f32x4 __attribute__((ext_vector_type(4)));

#define B_ 4
#define T_ 4096
#define D_ 1024
#define H_ 1024
#define M_ 16384   // B*T
#define N_ 2048    // 2H
#define K_ 1024
#define CHANS 4096 // B*H
#define CHUNKS 32
#define CLEN 128   // T / CHUNKS

#define BM 256
#define BN 256
#define BK 64
#define NT (K_ / BK) // 16 K-tiles

__device__ __forceinline__ u16 f2b(float f) {
    unsigned u = __float_as_uint(f);
    unsigned r = (u + 0x7FFFu + ((u >> 16) & 1u)) >> 16;
    return (u16)r;
}
__device__ __forceinline__ float b2f(u16 v) {
    return __uint_as_float(((unsigned)v) << 16);
}
__device__ __forceinline__ float sigm(float x) { return 1.f / (1.f + __expf(-x)); }

#define GLDS16(gp, lp)                                                         \
    __builtin_amdgcn_global_load_lds(                                          \
        (__attribute__((address_space(1))) void*)(gp),                         \
        (__attribute__((address_space(3))) void*)(lp), 16, 0, 0)

#define BAR() __builtin_amdgcn_s_barrier()
#define WAITLGKM()                                                             \
    do {                                                                       \
        asm volatile("s_waitcnt lgkmcnt(0)" ::: "memory");                     \
        __builtin_amdgcn_sched_barrier(0);                                     \
    } while (0)
#define WAITVM0()                                                              \
    do {                                                                       \
        asm volatile("s_waitcnt vmcnt(0)" ::: "memory");                       \
        __builtin_amdgcn_sched_barrier(0);                                     \
    } while (0)

// ---------------- convert x: fp32 -> bf16 ----------------
__global__ __launch_bounds__(256) void cvt_x(const float* __restrict__ in,
                                             u16* __restrict__ out, int n8) {
    int i = blockIdx.x * 256 + threadIdx.x;
    int stride = gridDim.x * 256;
    for (; i < n8; i += stride) {
        const float4* p = (const float4*)(in + (size_t)i * 8);
        float4 v0 = p[0], v1 = p[1];
        u16 o[8];
        o[0] = f2b(v0.x); o[1] = f2b(v0.y); o[2] = f2b(v0.z); o[3] = f2b(v0.w);
        o[4] = f2b(v1.x); o[5] = f2b(v1.y); o[6] = f2b(v1.z); o[7] = f2b(v1.w);
        *(uint4*)(out + (size_t)i * 8) = *(const uint4*)o;
    }
}

// ---------------- transpose + permute + convert W -> Wt [N][K] bf16 ----------
// column permutation: new col c <- orig col (c>>5)*16 + (c&15) + (c&16 ? 1024 : 0)
// (interleaves 16 gate cols then the matching 16 value cols per 32-group)
__global__ __launch_bounds__(256) void tr_w(const float* __restrict__ W,
                                            u16* __restrict__ Wt) {
    __shared__ float tile[32][33];
    int kt = blockIdx.x * 32;
    int nt = blockIdx.y * 32;
    int tx = threadIdx.x & 31;
    int ty = threadIdx.x >> 5; // 0..7
    int oc = (nt >> 5) * 16 + (tx & 15) + ((tx & 16) ? 1024 : 0);
#pragma unroll
    for (int i = 0; i < 4; ++i)
        tile[ty + i * 8][tx] = W[(size_t)(kt + ty + i * 8) * N_ + oc];
    __syncthreads();
#pragma unroll
    for (int i = 0; i < 4; ++i)
        Wt[(size_t)(nt + ty + i * 8) * K_ + kt + tx] = f2b(tile[tx][ty + i * 8]);
}

// ---------------- 256x256 8-wave 4-phase MFMA GEMM + fused sigmoid epilogue --
// A: [M][K] bf16; Bt: [N][K] bf16 (permuted cols); writes G (f32 M x H) and
// In (bf16 M x H) where G=sigmoid(pg+bg), In=(1-G)*(pv+bv).
__global__ __launch_bounds__(512, 2) void gemm_fused(const u16* __restrict__ A,
                                                     const u16* __restrict__ Bt,
                                                     const float* __restrict__ bias,
                                                     float* __restrict__ G,
                                                     u16* __restrict__ In) {
    // LDS: A dbuf 2x16384 u16, then B dbuf 2x16384 u16  (131072 B total)
    __shared__ u16 lds[65536];

    const int tid = threadIdx.x;
    const int w = tid >> 6;   // 0..7
    const int l = tid & 63;
    const int wm = w >> 2;    // 0..1  (M half)
    const int wn = w & 3;     // 0..3  (N quarter)

    // XCD-aware swizzle: 512 wgs, 8 XCDs -> contiguous 64-wg chunks per XCD
    int swz = (blockIdx.x & 7) * 64 + (blockIdx.x >> 3);
    const int brow = (swz >> 3) * BM; // 64 M-tiles
    const int bcol = (swz & 7) * BN;  // 8 N-tiles

    // ---- staging (global -> LDS, inverse-swizzled source, linear dest) ----
    const int srow = w * 8 + (l >> 3);        // 0..63 within 64-row chunk
    const int sgrn = (l & 7) ^ (l >> 3);      // pre-swizzled source granule
    const u16* aSrc = A + (size_t)(brow + srow) * K_ + sgrn * 8;
    const u16* bSrc = Bt + (size_t)(bcol + srow) * K_ + sgrn * 8;
    const int ldsW = w * 512 + l * 8; // u16 index, linear in lane

#define STAGE(cur, k0)                                                         \
    do {                                                                       \
        _Pragma("unroll") for (int j = 0; j < 4; ++j)                          \
            GLDS16(aSrc + (size_t)j * 64 * K_ + (k0),                          \
                   &lds[(cur)*16384 + j * 4096 + ldsW]);                       \
        _Pragma("unroll") for (int j = 0; j < 4; ++j)                          \
            GLDS16(bSrc + (size_t)j * 64 * K_ + (k0),                          \
                   &lds[32768 + (cur)*16384 + j * 4096 + ldsW]);               \
    } while (0)

    // ---- read-side fragment addressing (swizzled granule) ----
    const int lr = l & 15, lg = l >> 4, lx = l & 7;
    const int g80 = ((lg ^ lx) << 3);        // ks=0 granule byte/2 offset
    const int g81 = (((4 | lg) ^ lx) << 3);  // ks=1
    const int aRd = (wm * 128 + lr) * 64;    // u16 index base (A)
    const int bRd = 32768 + (wn * 64 + lr) * 64;

    f32x4 acc[8][4];
#pragma unroll
    for (int m = 0; m < 8; ++m)
#pragma unroll
        for (int n = 0; n < 4; ++n) acc[m][n] = (f32x4){0.f, 0.f, 0.f, 0.f};

    // prologue: stage tile 0 into buf 0
    STAGE(0, 0);
    WAITVM0();
    BAR();

#pragma unroll 1
    for (int t = 0; t < NT; ++t) {
        const int cur = t & 1;
        const int ab = cur * 16384;       // A buf base
        const int bb = cur * 16384;       // B buf extra base (bRd has +32768)

        bf16x8 af[4][2], b0r[2][2], b1r[2][2];

        // ---------- P1: stage next tile + read A(mf0-3), B(nf0-1) ----------
        if (t + 1 < NT) STAGE(cur ^ 1, (t + 1) * BK);
#pragma unroll
        for (int m = 0; m < 4; ++m) {
            af[m][0] = *(const bf16x8*)&lds[ab + aRd + m * 1024 + g80];
            af[m][1] = *(const bf16x8*)&lds[ab + aRd + m * 1024 + g81];
        }
#pragma unroll
        for (int n = 0; n < 2; ++n) {
            b0r[n][0] = *(const bf16x8*)&lds[bb + bRd + n * 1024 + g80];
            b0r[n][1] = *(const bf16x8*)&lds[bb + bRd + n * 1024 + g81];
        }
        BAR();
        WAITLGKM();
        __builtin_amdgcn_s_setprio(1);
#pragma unroll
        for (int m = 0; m < 4; ++m)
#pragma unroll
            for (int n = 0; n < 2; ++n)
#pragma unroll
                for (int ks = 0; ks < 2; ++ks)
                    acc[m][n] = __builtin_amdgcn_mfma_f32_16x16x32_bf16(
                        af[m][ks], b0r[n][ks], acc[m][n], 0, 0, 0);
        __builtin_amdgcn_s_setprio(0);
        BAR();

        // ---------- P2: read B(nf2-3) ----------
#pragma unroll
        for (int n = 0; n < 2; ++n) {
            b1r[n][0] = *(const bf16x8*)&lds[bb + bRd + (n + 2) * 1024 + g80];
            b1r[n][1] = *(const bf16x8*)&lds[bb + bRd + (n + 2) * 1024 + g81];
        }
        BAR();
        WAITLGKM();
        __builtin_amdgcn_s_setprio(1);
#pragma unroll
        for (int m = 0; m < 4; ++m)
#pragma unroll
            for (int n = 0; n < 2; ++n)
#pragma unroll
                for (int ks = 0; ks < 2; ++ks)
                    acc[m][n + 2] = __builtin_amdgcn_mfma_f32_16x16x32_bf16(
                        af[m][ks], b1r[n][ks], acc[m][n + 2], 0, 0, 0);
        __builtin_amdgcn_s_setprio(0);
        BAR();

        // ---------- P3: read A(mf4-7) ----------
#pragma unroll
        for (int m = 0; m < 4; ++m) {
            af[m][0] = *(const bf16x8*)&lds[ab + aRd + (m + 4) * 1024 + g80];
            af[m][1] = *(const bf16x8*)&lds[ab + aRd + (m + 4) * 1024 + g81];
        }
        BAR();
        WAITLGKM();
        __builtin_amdgcn_s_setprio(1);
#pragma unroll
        for (int m = 0; m < 4; ++m)
#pragma unroll
            for (int n = 0; n < 2; ++n)
#pragma unroll
                for (int ks = 0; ks < 2; ++ks)
                    acc[m + 4][n + 2] = __builtin_amdgcn_mfma_f32_16x16x32_bf16(
                        af[m][ks], b1r[n][ks], acc[m + 4][n + 2], 0, 0, 0);
        __builtin_amdgcn_s_setprio(0);
        BAR();

        // ---------- P4: MFMA only (regs live), then counted drain ----------
        __builtin_amdgcn_s_setprio(1);
#pragma unroll
        for (int m = 0; m < 4; ++m)
#pragma unroll
            for (int n = 0; n < 2; ++n)
#pragma unroll
                for (int ks = 0; ks < 2; ++ks)
                    acc[m + 4][n] = __builtin_amdgcn_mfma_f32_16x16x32_bf16(
                        af[m][ks], b0r[n][ks], acc[m + 4][n], 0, 0, 0);
        __builtin_amdgcn_s_setprio(0);
        WAITVM0(); // next tile's 8 loads (issued at P1) must land before reads
        BAR();
    }

    // ---- fused epilogue: g = sigmoid(pg+bg); in = (1-g)*(pv+bv) ----
    const int hb0 = ((bcol + wn * 64) >> 5) * 16;
    float bg[2], bv[2];
#pragma unroll
    for (int p = 0; p < 2; ++p) {
        bg[p] = bias[hb0 + p * 16 + lr];
        bv[p] = bias[H_ + hb0 + p * 16 + lr];
    }
#pragma unroll
    for (int m = 0; m < 8; ++m) {
        int rowb = brow + wm * 128 + m * 16 + lg * 4;
#pragma unroll
        for (int p = 0; p < 2; ++p) {
            int h = hb0 + p * 16 + lr;
#pragma unroll
            for (int j = 0; j < 4; ++j) {
                float pg = acc[m][2 * p][j] + bg[p];
                float pv = acc[m][2 * p + 1][j] + bv[p];
                float g = sigm(pg);
                float in = (1.f - g) * pv;
                size_t off = (size_t)(rowb + j) * H_ + h;
                G[off] = g;
                In[off] = f2b(in);
            }
        }
    }
}

// ---------------- scan pass A: per-(channel,chunk) affine aggregate ---------
__global__ __launch_bounds__(256) void scan_passA(const float* __restrict__ G,
                                                  const u16* __restrict__ In,
                                                  float* __restrict__ Aagg,
                                                  float* __restrict__ Uagg) {
    int i = blockIdx.x * 256 + threadIdx.x;
    int chan = i & (CHANS - 1);
    int chunk = i >> 12;
    int b = chan >> 10, h = chan & 1023;
    size_t base = ((size_t)b * T_ + (size_t)chunk * CLEN) * H_ + h;
    float a = 1.f, u = 0.f;
#pragma unroll 4
    for (int t = 0; t < CLEN; ++t) {
        float g = G[base];
        float in = b2f(In[base]);
        u = u * g + in;
        a *= g;
        base += H_;
    }
    Aagg[i] = a;
    Uagg[i] = u;
}

// ---------------- scan pass B: scan chunk aggregates ----------------
__global__ __launch_bounds__(256) void scan_passB(const float* __restrict__ Aagg,
                                                  const float* __restrict__ Uagg,
                                                  const float* __restrict__ state_in,
                                                  float* __restrict__ chunkH0,
                                                  float* __restrict__ state_out) {
    int chan = blockIdx.x * 256 + threadIdx.x;
    float h = state_in[chan];
#pragma unroll
    for (int c = 0; c < CHUNKS; ++c) {
        chunkH0[c * CHANS + chan] = h;
        h = Aagg[c * CHANS + chan] * h + Uagg[c * CHANS + chan];
    }
    state_out[chan] = h;
}

// ---------------- scan pass C: replay chunk, write h ----------------
template <int OUT_BF16>
__global__ __launch_bounds__(256) void scan_passC(const float* __restrict__ G,
                                                  const u16* __restrict__ In,
                                                  const float* __restrict__ chunkH0,
                                                  void* __restrict__ outp) {
    int i = blockIdx.x * 256 + threadIdx.x;
    int chan = i & (CHANS - 1);
    int chunk = i >> 12;
    int b = chan >> 10, h = chan & 1023;
    size_t base = ((size_t)b * T_ + (size_t)chunk * CLEN) * H_ + h;
    float hh = chunkH0[chunk * CHANS + chan];
#pragma unroll 4
    for (int t = 0; t < CLEN; ++t) {
        float g = G[base];
        float in = b2f(In[base]);
        hh = g * hh + in;
        if (OUT_BF16)
            ((u16*)outp)[base] = f2b(hh); // same M x H indexing
        else
            ((float*)outp)[base] = hh;
        base += H_;
    }
}

extern "C" void kernel_launch(void* const* d_in, const int* in_sizes, int n_in,
                              void* d_out, int out_size, void* d_ws, size_t ws_size,
                              hipStream_t stream) {
    const float* x = (const float*)d_in[0];
    const float* W0 = (const float*)d_in[1];
    const float* b0 = (const float*)d_in[2];
    const float* W1 = (const float*)d_in[3];
    const float* b1 = (const float*)d_in[4];
    const float* state = (const float*)d_in[5];
    float* out = (float*)d_out;

    char* ws = (char*)d_ws;
    u16* xb = (u16*)ws;                      // 33,554,432 B
    u16* h1b = (u16*)(ws + 33554432);        // 33,554,432 B
    u16* Wt = (u16*)(ws + 67108864);         // 8,388,608 B
    float* Gbuf = (float*)(ws + 75497472);   // 67,108,864 B
    u16* Inb = (u16*)(ws + 142606336);       // 33,554,432 B
    float* Aagg = (float*)(ws + 176160768);  // 524,288 B
    float* Uagg = (float*)(ws + 176685056);  // 524,288 B
    float* cH0 = (float*)(ws + 177209344);   // 524,288 B

    cvt_x<<<2048, 256, 0, stream>>>(x, xb, M_ * K_ / 8);
    tr_w<<<dim3(32, 64), 256, 0, stream>>>(W0, Wt);
    tr_w<<<dim3(32, 64), 256, 0, stream>>>(W1, Wt + (size_t)N_ * K_);

    for (int l = 0; l < 2; ++l) {
        const u16* Aop = l ? h1b : xb;
        const float* bias = l ? b1 : b0;
        gemm_fused<<<(M_ / BM) * (N_ / BN), 512, 0, stream>>>(
            Aop, Wt + (size_t)l * N_ * K_, bias, Gbuf, Inb);
        scan_passA<<<(CHANS * CHUNKS) / 256, 256, 0, stream>>>(Gbuf, Inb, Aagg, Uagg);
        scan_passB<<<CHANS / 256, 256, 0, stream>>>(
            Aagg, Uagg, state + (size_t)l * CHANS, cH0,
            out + (size_t)M_ * H_ + (size_t)l * CHANS);
        if (l == 0)
            scan_passC<1><<<(CHANS * CHUNKS) / 256, 256, 0, stream>>>(Gbuf, Inb, cH0, h1b);
        else
            scan_passC<0><<<(CHANS * CHUNKS) / 256, 256, 0, stream>>>(Gbuf, Inb, cH0, out);
    }
}

// Round 3
// 270.247 us; speedup vs baseline: 1.3704x; 1.0391x over previous
//
#include <hip/hip_runtime.h>

typedef unsigned short u16;
typedef unsigned int u32;
typedef __bf16 bf16x8 __attribute__((ext_vector_type(8)));
typedef float f32x4 __attribute__((ext_vector_type(4)));

#define B_ 4
#define T_ 4096
#define D_ 1024
#define H_ 1024
#define M_ 16384   // B*T
#define N_ 2048    // 2H
#define K_ 1024
#define CHANS 4096 // B*H
#define CHUNKS 32
#define CLEN 128   // T / CHUNKS

#define BM 256
#define BN 256
#define BK 64
#define NT (K_ / BK) // 16 K-tiles

__device__ __forceinline__ u16 f2b(float f) {
    unsigned u = __float_as_uint(f);
    unsigned r = (u + 0x7FFFu + ((u >> 16) & 1u)) >> 16;
    return (u16)r;
}
__device__ __forceinline__ float b2f(u32 hi16) { // takes value<<16 already? no: pass u16
    return __uint_as_float(hi16 << 16);
}
__device__ __forceinline__ float sigm(float x) { return 1.f / (1.f + __expf(-x)); }

#define GLDS16(gp, lp)                                                         \
    __builtin_amdgcn_global_load_lds(                                          \
        (__attribute__((address_space(1))) void*)(gp),                         \
        (__attribute__((address_space(3))) void*)(lp), 16, 0, 0)

#define BAR() __builtin_amdgcn_s_barrier()
#define WAITLGKM()                                                             \
    do {                                                                       \
        asm volatile("s_waitcnt lgkmcnt(0)" ::: "memory");                     \
        __builtin_amdgcn_sched_barrier(0);                                     \
    } while (0)
#define WAITVM(N)                                                              \
    do {                                                                       \
        asm volatile("s_waitcnt vmcnt(" #N ")" ::: "memory");                  \
        __builtin_amdgcn_sched_barrier(0);                                     \
    } while (0)

// ---------------- convert x: fp32 -> bf16 ----------------
__global__ __launch_bounds__(256) void cvt_x(const float* __restrict__ in,
                                             u16* __restrict__ out, int n8) {
    int i = blockIdx.x * 256 + threadIdx.x;
    int stride = gridDim.x * 256;
    for (; i < n8; i += stride) {
        const float4* p = (const float4*)(in + (size_t)i * 8);
        float4 v0 = p[0], v1 = p[1];
        u16 o[8];
        o[0] = f2b(v0.x); o[1] = f2b(v0.y); o[2] = f2b(v0.z); o[3] = f2b(v0.w);
        o[4] = f2b(v1.x); o[5] = f2b(v1.y); o[6] = f2b(v1.z); o[7] = f2b(v1.w);
        *(uint4*)(out + (size_t)i * 8) = *(const uint4*)o;
    }
}

// ---------------- transpose + permute + convert W -> Wt [N][K] bf16 ----------
// permuted col c <- orig col (c>>5)*16 + (c&15) + (c&16 ? 1024 : 0)
__global__ __launch_bounds__(256) void tr_w(const float* __restrict__ W,
                                            u16* __restrict__ Wt) {
    __shared__ float tile[32][33];
    int kt = blockIdx.x * 32;
    int nt = blockIdx.y * 32;
    int tx = threadIdx.x & 31;
    int ty = threadIdx.x >> 5;
    int oc = (nt >> 5) * 16 + (tx & 15) + ((tx & 16) ? 1024 : 0);
#pragma unroll
    for (int i = 0; i < 4; ++i)
        tile[ty + i * 8][tx] = W[(size_t)(kt + ty + i * 8) * N_ + oc];
    __syncthreads();
#pragma unroll
    for (int i = 0; i < 4; ++i)
        Wt[(size_t)(nt + ty + i * 8) * K_ + kt + tx] = f2b(tile[tx][ty + i * 8]);
}

// ---------------- 256x256 8-wave GEMM, staggered staging + counted vmcnt ----
// Writes GI (u32 M x H): low16 = g quantized u16 fixed-point, high16 = bf16 in.
__global__ __launch_bounds__(512, 2) void gemm_fused(const u16* __restrict__ A,
                                                     const u16* __restrict__ Bt,
                                                     const float* __restrict__ bias,
                                                     u32* __restrict__ GI) {
    // LDS u16 units: [Abuf0 16384][Abuf1 16384][Bbuf0 16384][Bbuf1 16384]
    __shared__ u16 lds[65536];

    const int tid = threadIdx.x;
    const int w = tid >> 6;
    const int l = tid & 63;
    const int wm = w >> 2;
    const int wn = w & 3;

    int swz = (blockIdx.x & 7) * 64 + (blockIdx.x >> 3);
    const int brow = (swz >> 3) * BM;
    const int bcol = (swz & 7) * BN;

    // staging maps (linear LDS dest = wave-uniform + l*16B; swizzled source)
    const int r64 = w * 8 + (l >> 3);           // 0..63
    const int sg8 = (((l & 7) ^ (l >> 3)) << 3); // pre-swizzled source granule (u16)
    const u16* aS = A + (size_t)(brow + r64) * K_ + sg8;
    const u16* bS = Bt + (size_t)(bcol + r64 + ((w >= 4) ? 32 : 0)) * K_ + sg8;
    const int aD = w * 512 + l * 8;                        // u16 index
    const int bD = ((w >= 4) ? 2048 : 0) + w * 512 + l * 8;

    // G1: A rows {r64, 128+r64} + B rows {bs, 128+bs}      (4 loads)
    // G2: B rows {32+bs, 160+bs}                           (2 loads)
    // G3: A rows {64+r64, 192+r64}                         (2 loads)
#define STAGE_G1(nab, nbb, k0)                                                 \
    do {                                                                       \
        GLDS16(aS + (k0), &lds[(nab) + aD]);                                   \
        GLDS16(aS + 128 * K_ + (k0), &lds[(nab) + aD + 8192]);                 \
        GLDS16(bS + (k0), &lds[(nbb) + bD]);                                   \
        GLDS16(bS + 128 * K_ + (k0), &lds[(nbb) + bD + 8192]);                 \
    } while (0)
#define STAGE_G2(nbb, k0)                                                      \
    do {                                                                       \
        GLDS16(bS + 32 * K_ + (k0), &lds[(nbb) + bD + 2048]);                  \
        GLDS16(bS + 160 * K_ + (k0), &lds[(nbb) + bD + 2048 + 8192]);          \
    } while (0)
#define STAGE_G3(nab, k0)                                                      \
    do {                                                                       \
        GLDS16(aS + 64 * K_ + (k0), &lds[(nab) + aD + 4096]);                  \
        GLDS16(aS + 192 * K_ + (k0), &lds[(nab) + aD + 12288]);                \
    } while (0)

    // read-side fragment addressing (swizzled granule), as round-2 (verified)
    const int lr = l & 15, lg = l >> 4, lx = l & 7;
    const int g80 = ((lg ^ lx) << 3);
    const int g81 = (((4 | lg) ^ lx) << 3);
    const int aRd = (wm * 128 + lr) * 64;
    const int bRd = (wn * 64 + lr) * 64;

    f32x4 acc[8][4];
#pragma unroll
    for (int m = 0; m < 8; ++m)
#pragma unroll
        for (int n = 0; n < 4; ++n) acc[m][n] = (f32x4){0.f, 0.f, 0.f, 0.f};

    // prologue: full tile 0 into buf 0, full drain once
    STAGE_G1(0, 32768, 0);
    STAGE_G2(32768, 0);
    STAGE_G3(0, 0);
    WAITVM(0);
    BAR();

#pragma unroll 1
    for (int t = 0; t < NT; ++t) {
        const int cur = t & 1;
        const int ab = cur * 16384;
        const int bb = 32768 + cur * 16384;
        const int nab = (cur ^ 1) * 16384;
        const int nbb = 32768 + (cur ^ 1) * 16384;
        const int nk = (t + 1) * BK;

        bf16x8 af[4][2], b0r[2][2], b1r[2][2];

        // -------- P1: stage G1(t+1); read F1; vmcnt(4) drains G2,G3(t) ------
        if (t + 1 < NT) STAGE_G1(nab, nbb, nk);
#pragma unroll
        for (int m = 0; m < 4; ++m) {
            af[m][0] = *(const bf16x8*)&lds[ab + aRd + m * 1024 + g80];
            af[m][1] = *(const bf16x8*)&lds[ab + aRd + m * 1024 + g81];
        }
#pragma unroll
        for (int n = 0; n < 2; ++n) {
            b0r[n][0] = *(const bf16x8*)&lds[bb + bRd + n * 1024 + g80];
            b0r[n][1] = *(const bf16x8*)&lds[bb + bRd + n * 1024 + g81];
        }
        if (t + 1 < NT) { WAITVM(4); } else { WAITVM(0); }
        BAR();
        WAITLGKM();
        __builtin_amdgcn_s_setprio(1);
#pragma unroll
        for (int m = 0; m < 4; ++m)
#pragma unroll
            for (int n = 0; n < 2; ++n)
#pragma unroll
                for (int ks = 0; ks < 2; ++ks)
                    acc[m][n] = __builtin_amdgcn_mfma_f32_16x16x32_bf16(
                        af[m][ks], b0r[n][ks], acc[m][n], 0, 0, 0);
        __builtin_amdgcn_s_setprio(0);

        // -------- P2: stage G2(t+1); read F2 (B odd eighths) ---------------
        if (t + 1 < NT) STAGE_G2(nbb, nk);
#pragma unroll
        for (int n = 0; n < 2; ++n) {
            b1r[n][0] = *(const bf16x8*)&lds[bb + bRd + (n + 2) * 1024 + g80];
            b1r[n][1] = *(const bf16x8*)&lds[bb + bRd + (n + 2) * 1024 + g81];
        }
        BAR();
        WAITLGKM();
        __builtin_amdgcn_s_setprio(1);
#pragma unroll
        for (int m = 0; m < 4; ++m)
#pragma unroll
            for (int n = 0; n < 2; ++n)
#pragma unroll
                for (int ks = 0; ks < 2; ++ks)
                    acc[m][n + 2] = __builtin_amdgcn_mfma_f32_16x16x32_bf16(
                        af[m][ks], b1r[n][ks], acc[m][n + 2], 0, 0, 0);
        __builtin_amdgcn_s_setprio(0);

        // -------- P3: stage G3(t+1); read F3 (A quarters 1,3) --------------
        if (t + 1 < NT) STAGE_G3(nab, nk);
#pragma unroll
        for (int m = 0; m < 4; ++m) {
            af[m][0] = *(const bf16x8*)&lds[ab + aRd + (m + 4) * 1024 + g80];
            af[m][1] = *(const bf16x8*)&lds[ab + aRd + (m + 4) * 1024 + g81];
        }
        BAR();
        WAITLGKM();
        __builtin_amdgcn_s_setprio(1);
#pragma unroll
        for (int m = 0; m < 4; ++m)
#pragma unroll
            for (int n = 0; n < 2; ++n)
#pragma unroll
                for (int ks = 0; ks < 2; ++ks)
                    acc[m + 4][n + 2] = __builtin_amdgcn_mfma_f32_16x16x32_bf16(
                        af[m][ks], b1r[n][ks], acc[m + 4][n + 2], 0, 0, 0);
        __builtin_amdgcn_s_setprio(0);

        // -------- P4: regs only; boundary vmcnt(4) drains G1(t+1) ----------
        __builtin_amdgcn_s_setprio(1);
#pragma unroll
        for (int m = 0; m < 4; ++m)
#pragma unroll
            for (int n = 0; n < 2; ++n)
#pragma unroll
                for (int ks = 0; ks < 2; ++ks)
                    acc[m + 4][n] = __builtin_amdgcn_mfma_f32_16x16x32_bf16(
                        af[m][ks], b0r[n][ks], acc[m + 4][n], 0, 0, 0);
        __builtin_amdgcn_s_setprio(0);
        WAITVM(4);
        BAR();
    }

    // ---- fused epilogue: pack g (u16 fixed-point) | in (bf16) into u32 ----
    const int hb0 = ((bcol + wn * 64) >> 5) * 16;
    float bg[2], bv[2];
#pragma unroll
    for (int p = 0; p < 2; ++p) {
        bg[p] = bias[hb0 + p * 16 + lr];
        bv[p] = bias[H_ + hb0 + p * 16 + lr];
    }
#pragma unroll
    for (int m = 0; m < 8; ++m) {
        int rowb = brow + wm * 128 + m * 16 + lg * 4;
#pragma unroll
        for (int p = 0; p < 2; ++p) {
            int h = hb0 + p * 16 + lr;
#pragma unroll
            for (int j = 0; j < 4; ++j) {
                float pg = acc[m][2 * p][j] + bg[p];
                float pv = acc[m][2 * p + 1][j] + bv[p];
                float g = sigm(pg);
                float in = (1.f - g) * pv;
                u32 gq = __float2uint_rn(g * 65535.f);
                GI[(size_t)(rowb + j) * H_ + h] = ((u32)f2b(in) << 16) | gq;
            }
        }
    }
}

// ---------------- scan pass A: per-(chan-pair,chunk) aggregate --------------
__global__ __launch_bounds__(256) void scan_passA(const u32* __restrict__ GI,
                                                  float* __restrict__ Aagg,
                                                  float* __restrict__ Uagg) {
    int i = blockIdx.x * 256 + threadIdx.x; // [0, 65536)
    int cp = i & 2047;
    int chunk = i >> 11;
    int b = cp >> 9, h2 = cp & 511;
    const uint2* p = (const uint2*)GI + ((size_t)(b * T_ + chunk * CLEN) * (H_ / 2) + h2);
    const float inv = 1.f / 65535.f;
    float a0 = 1.f, u0 = 0.f, a1 = 1.f, u1 = 0.f;
#pragma unroll 4
    for (int t = 0; t < CLEN; ++t) {
        uint2 v = *p;
        float g0 = (float)(v.x & 0xffffu) * inv, in0 = b2f(v.x >> 16);
        float g1 = (float)(v.y & 0xffffu) * inv, in1 = b2f(v.y >> 16);
        u0 = u0 * g0 + in0; a0 *= g0;
        u1 = u1 * g1 + in1; a1 *= g1;
        p += H_ / 2;
    }
    int chan = b * 1024 + h2 * 2;
    *(float2*)&Aagg[(size_t)chunk * CHANS + chan] = make_float2(a0, a1);
    *(float2*)&Uagg[(size_t)chunk * CHANS + chan] = make_float2(u0, u1);
}

// ---------------- scan pass B: scan chunk aggregates ----------------
__global__ __launch_bounds__(256) void scan_passB(const float* __restrict__ Aagg,
                                                  const float* __restrict__ Uagg,
                                                  const float* __restrict__ state_in,
                                                  float* __restrict__ chunkH0,
                                                  float* __restrict__ state_out) {
    int chan = blockIdx.x * 256 + threadIdx.x;
    float h = state_in[chan];
#pragma unroll
    for (int c = 0; c < CHUNKS; ++c) {
        chunkH0[c * CHANS + chan] = h;
        h = Aagg[c * CHANS + chan] * h + Uagg[c * CHANS + chan];
    }
    state_out[chan] = h;
}

// ---------------- scan pass C: replay chunk, write h ----------------
template <int OUT_BF16>
__global__ __launch_bounds__(256) void scan_passC(const u32* __restrict__ GI,
                                                  const float* __restrict__ chunkH0,
                                                  void* __restrict__ outp) {
    int i = blockIdx.x * 256 + threadIdx.x;
    int cp = i & 2047;
    int chunk = i >> 11;
    int b = cp >> 9, h2 = cp & 511;
    size_t rowu = (size_t)(b * T_ + chunk * CLEN) * (H_ / 2) + h2;
    const uint2* p = (const uint2*)GI + rowu;
    const float inv = 1.f / 65535.f;
    int chan = b * 1024 + h2 * 2;
    float h0v = chunkH0[(size_t)chunk * CHANS + chan];
    float h1v = chunkH0[(size_t)chunk * CHANS + chan + 1];
#pragma unroll 4
    for (int t = 0; t < CLEN; ++t) {
        uint2 v = *p;
        float g0 = (float)(v.x & 0xffffu) * inv, in0 = b2f(v.x >> 16);
        float g1 = (float)(v.y & 0xffffu) * inv, in1 = b2f(v.y >> 16);
        h0v = g0 * h0v + in0;
        h1v = g1 * h1v + in1;
        if (OUT_BF16) {
            ((u32*)outp)[rowu] = (u32)f2b(h0v) | ((u32)f2b(h1v) << 16);
        } else {
            ((float2*)outp)[rowu] = make_float2(h0v, h1v);
        }
        p += H_ / 2;
        rowu += H_ / 2;
    }
}

extern "C" void kernel_launch(void* const* d_in, const int* in_sizes, int n_in,
                              void* d_out, int out_size, void* d_ws, size_t ws_size,
                              hipStream_t stream) {
    const float* x = (const float*)d_in[0];
    const float* W0 = (const float*)d_in[1];
    const float* b0 = (const float*)d_in[2];
    const float* W1 = (const float*)d_in[3];
    const float* b1 = (const float*)d_in[4];
    const float* state = (const float*)d_in[5];
    float* out = (float*)d_out;

    char* ws = (char*)d_ws;
    u16* xb = (u16*)ws;                     // 33,554,432 B
    u16* h1b = (u16*)(ws + 33554432);       // 33,554,432 B
    u16* Wt = (u16*)(ws + 67108864);        // 8,388,608 B
    u32* GIb = (u32*)(ws + 75497472);       // 67,108,864 B
    float* Aagg = (float*)(ws + 142606336); // 524,288 B
    float* Uagg = (float*)(ws + 143130624); // 524,288 B
    float* cH0 = (float*)(ws + 143654912);  // 524,288 B

    cvt_x<<<2048, 256, 0, stream>>>(x, xb, M_ * K_ / 8);
    tr_w<<<dim3(32, 64), 256, 0, stream>>>(W0, Wt);
    tr_w<<<dim3(32, 64), 256, 0, stream>>>(W1, Wt + (size_t)N_ * K_);

    for (int l = 0; l < 2; ++l) {
        const u16* Aop = l ? h1b : xb;
        const float* bias = l ? b1 : b0;
        gemm_fused<<<(M_ / BM) * (N_ / BN), 512, 0, stream>>>(
            Aop, Wt + (size_t)l * N_ * K_, bias, GIb);
        scan_passA<<<(CHANS * CHUNKS / 2) / 256, 256, 0, stream>>>(GIb, Aagg, Uagg);
        scan_passB<<<CHANS / 256, 256, 0, stream>>>(
            Aagg, Uagg, state + (size_t)l * CHANS, cH0,
            out + (size_t)M_ * H_ + (size_t)l * CHANS);
        if (l == 0)
            scan_passC<1><<<(CHANS * CHUNKS / 2) / 256, 256, 0, stream>>>(GIb, cH0, h1b);
        else
            scan_passC<0><<<(CHANS * CHUNKS / 2) / 256, 256, 0, stream>>>(GIb, cH0, out);
    }
}

// Round 4
// 244.390 us; speedup vs baseline: 1.5154x; 1.1058x over previous
//
#include <hip/hip_runtime.h>

typedef unsigned short u16;
typedef unsigned int u32;
typedef __bf16 bf16x8 __attribute__((ext_vector_type(8)));
typedef float f32x4 __attribute__((ext_vector_type(4)));

#define B_ 4
#define T_ 4096
#define D_ 1024
#define H_ 1024
#define M_ 16384   // B*T
#define N_ 2048    // 2H
#define K_ 1024
#define CHANS 4096 // B*H
#define CHUNKS 32
#define CLEN 128   // T / CHUNKS

#define BM 256
#define BN 256
#define BK 64
#define NT (K_ / BK) // 16 K-tiles

__device__ __forceinline__ u16 f2b(float f) {
    unsigned u = __float_as_uint(f);
    unsigned r = (u + 0x7FFFu + ((u >> 16) & 1u)) >> 16;
    return (u16)r;
}
__device__ __forceinline__ float b2f(u32 v) {
    return __uint_as_float(v << 16);
}
__device__ __forceinline__ float sigm(float x) { return 1.f / (1.f + __expf(-x)); }

#define GLDS16(gp, lp)                                                         \
    __builtin_amdgcn_global_load_lds(                                          \
        (__attribute__((address_space(1))) void*)(gp),                         \
        (__attribute__((address_space(3))) void*)(lp), 16, 0, 0)

#define BAR() __builtin_amdgcn_s_barrier()
#define WAITLGKM()                                                             \
    do {                                                                       \
        asm volatile("s_waitcnt lgkmcnt(0)" ::: "memory");                     \
        __builtin_amdgcn_sched_barrier(0);                                     \
    } while (0)
#define WAITVM(N)                                                              \
    do {                                                                       \
        asm volatile("s_waitcnt vmcnt(" #N ")" ::: "memory");                  \
        __builtin_amdgcn_sched_barrier(0);                                     \
    } while (0)

// ---------------- convert x: fp32 -> bf16 ----------------
__global__ __launch_bounds__(256) void cvt_x(const float* __restrict__ in,
                                             u16* __restrict__ out, int n8) {
    int i = blockIdx.x * 256 + threadIdx.x;
    int stride = gridDim.x * 256;
    for (; i < n8; i += stride) {
        const float4* p = (const float4*)(in + (size_t)i * 8);
        float4 v0 = p[0], v1 = p[1];
        u16 o[8];
        o[0] = f2b(v0.x); o[1] = f2b(v0.y); o[2] = f2b(v0.z); o[3] = f2b(v0.w);
        o[4] = f2b(v1.x); o[5] = f2b(v1.y); o[6] = f2b(v1.z); o[7] = f2b(v1.w);
        *(uint4*)(out + (size_t)i * 8) = *(const uint4*)o;
    }
}

// ---------------- transpose + permute + convert W -> Wt [N][K] bf16 ----------
// permuted col c <- orig col (c>>5)*16 + (c&15) + (c&16 ? 1024 : 0)
__global__ __launch_bounds__(256) void tr_w(const float* __restrict__ W,
                                            u16* __restrict__ Wt) {
    __shared__ float tile[32][33];
    int kt = blockIdx.x * 32;
    int nt = blockIdx.y * 32;
    int tx = threadIdx.x & 31;
    int ty = threadIdx.x >> 5;
    int oc = (nt >> 5) * 16 + (tx & 15) + ((tx & 16) ? 1024 : 0);
#pragma unroll
    for (int i = 0; i < 4; ++i)
        tile[ty + i * 8][tx] = W[(size_t)(kt + ty + i * 8) * N_ + oc];
    __syncthreads();
#pragma unroll
    for (int i = 0; i < 4; ++i)
        Wt[(size_t)(nt + ty + i * 8) * K_ + kt + tx] = f2b(tile[tx][ty + i * 8]);
}

// ---------------- 256x256 8-wave GEMM + fused sigmoid + fused chunk-aggregate
// Writes GI (u32 M x H): low16 = g u16 fixed-point, high16 = bf16 in.
// Also writes per-(chunk,chan) affine aggregates Aagg/Uagg (passA fused).
__global__ __launch_bounds__(512, 2) void gemm_fused(const u16* __restrict__ A,
                                                     const u16* __restrict__ Bt,
                                                     const float* __restrict__ bias,
                                                     u32* __restrict__ GI,
                                                     float* __restrict__ Aagg,
                                                     float* __restrict__ Uagg) {
    // LDS u16 units: [Abuf0 16384][Abuf1 16384][Bbuf0 16384][Bbuf1 16384]
    __shared__ u16 lds[65536];

    const int tid = threadIdx.x;
    const int w = tid >> 6;
    const int l = tid & 63;
    const int wm = w >> 2;
    const int wn = w & 3;

    int swz = (blockIdx.x & 7) * 64 + (blockIdx.x >> 3);
    const int brow = (swz >> 3) * BM;
    const int bcol = (swz & 7) * BN;

    // staging maps (linear LDS dest; swizzled source granule)
    const int r64 = w * 8 + (l >> 3);
    const int sg8 = (((l & 7) ^ (l >> 3)) << 3);
    const u16* aS = A + (size_t)(brow + r64) * K_ + sg8;
    const u16* bS = Bt + (size_t)(bcol + r64 + ((w >= 4) ? 32 : 0)) * K_ + sg8;
    const int aD = w * 512 + l * 8;
    const int bD = ((w >= 4) ? 2048 : 0) + w * 512 + l * 8;

#define STAGE_G1(nab, nbb, k0)                                                 \
    do {                                                                       \
        GLDS16(aS + (k0), &lds[(nab) + aD]);                                   \
        GLDS16(aS + 128 * K_ + (k0), &lds[(nab) + aD + 8192]);                 \
        GLDS16(bS + (k0), &lds[(nbb) + bD]);                                   \
        GLDS16(bS + 128 * K_ + (k0), &lds[(nbb) + bD + 8192]);                 \
    } while (0)
#define STAGE_G2(nbb, k0)                                                      \
    do {                                                                       \
        GLDS16(bS + 32 * K_ + (k0), &lds[(nbb) + bD + 2048]);                  \
        GLDS16(bS + 160 * K_ + (k0), &lds[(nbb) + bD + 2048 + 8192]);          \
    } while (0)
#define STAGE_G3(nab, k0)                                                      \
    do {                                                                       \
        GLDS16(aS + 64 * K_ + (k0), &lds[(nab) + aD + 4096]);                  \
        GLDS16(aS + 192 * K_ + (k0), &lds[(nab) + aD + 12288]);                \
    } while (0)

    // read-side fragment addressing (swizzled granule)
    const int lr = l & 15, lg = l >> 4, lx = l & 7;
    const int g80 = ((lg ^ lx) << 3);
    const int g81 = (((4 | lg) ^ lx) << 3);
    const int aRd = (wm * 128 + lr) * 64;
    const int bRd = (wn * 64 + lr) * 64;

    f32x4 acc[8][4];
#pragma unroll
    for (int m = 0; m < 8; ++m)
#pragma unroll
        for (int n = 0; n < 4; ++n) acc[m][n] = (f32x4){0.f, 0.f, 0.f, 0.f};

    // prologue: full tile 0 into buf 0
    STAGE_G1(0, 32768, 0);
    STAGE_G2(32768, 0);
    STAGE_G3(0, 0);
    WAITVM(0);
    BAR();

#pragma unroll 1
    for (int t = 0; t < NT; ++t) {
        const int cur = t & 1;
        const int ab = cur * 16384;
        const int bb = 32768 + cur * 16384;
        const int nab = (cur ^ 1) * 16384;
        const int nbb = 32768 + (cur ^ 1) * 16384;
        const int nk = (t + 1) * BK;

        bf16x8 af[4][2], b0r[2][2], b1r[2][2];

        // -------- P1: stage G1(t+1); read F1; vmcnt(4) drains G2,G3(t) ------
        if (t + 1 < NT) STAGE_G1(nab, nbb, nk);
#pragma unroll
        for (int m = 0; m < 4; ++m) {
            af[m][0] = *(const bf16x8*)&lds[ab + aRd + m * 1024 + g80];
            af[m][1] = *(const bf16x8*)&lds[ab + aRd + m * 1024 + g81];
        }
#pragma unroll
        for (int n = 0; n < 2; ++n) {
            b0r[n][0] = *(const bf16x8*)&lds[bb + bRd + n * 1024 + g80];
            b0r[n][1] = *(const bf16x8*)&lds[bb + bRd + n * 1024 + g81];
        }
        if (t + 1 < NT) { WAITVM(4); } else { WAITVM(0); }
        BAR();
        WAITLGKM();
        __builtin_amdgcn_s_setprio(1);
#pragma unroll
        for (int m = 0; m < 4; ++m)
#pragma unroll
            for (int n = 0; n < 2; ++n)
#pragma unroll
                for (int ks = 0; ks < 2; ++ks)
                    acc[m][n] = __builtin_amdgcn_mfma_f32_16x16x32_bf16(
                        af[m][ks], b0r[n][ks], acc[m][n], 0, 0, 0);
        __builtin_amdgcn_s_setprio(0);

        // -------- P2: stage G2(t+1); read F2 (no barrier: buffer stable) ----
        if (t + 1 < NT) STAGE_G2(nbb, nk);
#pragma unroll
        for (int n = 0; n < 2; ++n) {
            b1r[n][0] = *(const bf16x8*)&lds[bb + bRd + (n + 2) * 1024 + g80];
            b1r[n][1] = *(const bf16x8*)&lds[bb + bRd + (n + 2) * 1024 + g81];
        }
        WAITLGKM();
        __builtin_amdgcn_s_setprio(1);
#pragma unroll
        for (int m = 0; m < 4; ++m)
#pragma unroll
            for (int n = 0; n < 2; ++n)
#pragma unroll
                for (int ks = 0; ks < 2; ++ks)
                    acc[m][n + 2] = __builtin_amdgcn_mfma_f32_16x16x32_bf16(
                        af[m][ks], b1r[n][ks], acc[m][n + 2], 0, 0, 0);
        __builtin_amdgcn_s_setprio(0);

        // -------- P3: stage G3(t+1); read F3 (no barrier) -------------------
        if (t + 1 < NT) STAGE_G3(nab, nk);
#pragma unroll
        for (int m = 0; m < 4; ++m) {
            af[m][0] = *(const bf16x8*)&lds[ab + aRd + (m + 4) * 1024 + g80];
            af[m][1] = *(const bf16x8*)&lds[ab + aRd + (m + 4) * 1024 + g81];
        }
        WAITLGKM();
        __builtin_amdgcn_s_setprio(1);
#pragma unroll
        for (int m = 0; m < 4; ++m)
#pragma unroll
            for (int n = 0; n < 2; ++n)
#pragma unroll
                for (int ks = 0; ks < 2; ++ks)
                    acc[m + 4][n + 2] = __builtin_amdgcn_mfma_f32_16x16x32_bf16(
                        af[m][ks], b1r[n][ks], acc[m + 4][n + 2], 0, 0, 0);
        __builtin_amdgcn_s_setprio(0);

        // -------- P4: regs only; boundary vmcnt(4) drains G1(t+1) -----------
        __builtin_amdgcn_s_setprio(1);
#pragma unroll
        for (int m = 0; m < 4; ++m)
#pragma unroll
            for (int n = 0; n < 2; ++n)
#pragma unroll
                for (int ks = 0; ks < 2; ++ks)
                    acc[m + 4][n] = __builtin_amdgcn_mfma_f32_16x16x32_bf16(
                        af[m][ks], b0r[n][ks], acc[m + 4][n], 0, 0, 0);
        __builtin_amdgcn_s_setprio(0);
        WAITVM(4);
        BAR();
    }

    // ---- fused epilogue: pack g|in, and compute chunk affine aggregate ----
    // wave rows = [brow + wm*128, +128) == exactly one scan chunk.
    const int hb0 = ((bcol + wn * 64) >> 5) * 16;
    float bg[2], bv[2];
#pragma unroll
    for (int p = 0; p < 2; ++p) {
        bg[p] = bias[hb0 + p * 16 + lr];
        bv[p] = bias[H_ + hb0 + p * 16 + lr];
    }
    float atot[2] = {1.f, 1.f}, utot[2] = {0.f, 0.f};
#pragma unroll
    for (int m = 0; m < 8; ++m) {
        int rowb = brow + wm * 128 + m * 16 + lg * 4;
#pragma unroll
        for (int p = 0; p < 2; ++p) {
            int h = hb0 + p * 16 + lr;
            float am = 1.f, um = 0.f;
#pragma unroll
            for (int j = 0; j < 4; ++j) {
                float pg = acc[m][2 * p][j] + bg[p];
                float pv = acc[m][2 * p + 1][j] + bv[p];
                float g = sigm(pg);
                float in = (1.f - g) * pv;
                u32 gq = __float2uint_rn(g * 65535.f);
                GI[(size_t)(rowb + j) * H_ + h] = ((u32)f2b(in) << 16) | gq;
                um = um * g + in; // j ascending composition
                am = am * g;
            }
            // ordered cross-lg composition (lg = bits 4-5 of lane)
            float pa = __shfl_xor(am, 16), pu = __shfl_xor(um, 16);
            float a2, u2;
            if (lg & 1) { a2 = pa * am; u2 = pu * am + um; }
            else        { a2 = am * pa; u2 = um * pa + pu; }
            float qa = __shfl_xor(a2, 32), qu = __shfl_xor(u2, 32);
            float a4, u4;
            if (lg & 2) { a4 = qa * a2; u4 = qu * a2 + u2; }
            else        { a4 = a2 * qa; u4 = u2 * qa + qu; }
            // m ascending composition
            utot[p] = utot[p] * a4 + u4;
            atot[p] = atot[p] * a4;
        }
    }
    if (lg == 0) {
        int R = brow + wm * 128;
        int bidx = R >> 12;             // batch
        int tchunk = (R >> 7) & 31;     // chunk within batch
#pragma unroll
        for (int p = 0; p < 2; ++p) {
            int chan = bidx * 1024 + hb0 + p * 16 + lr;
            Aagg[(size_t)tchunk * CHANS + chan] = atot[p];
            Uagg[(size_t)tchunk * CHANS + chan] = utot[p];
        }
    }
}

// ---------------- scan pass B: scan chunk aggregates ----------------
__global__ __launch_bounds__(256) void scan_passB(const float* __restrict__ Aagg,
                                                  const float* __restrict__ Uagg,
                                                  const float* __restrict__ state_in,
                                                  float* __restrict__ chunkH0,
                                                  float* __restrict__ state_out) {
    int chan = blockIdx.x * 256 + threadIdx.x;
    float h = state_in[chan];
#pragma unroll
    for (int c = 0; c < CHUNKS; ++c) {
        chunkH0[c * CHANS + chan] = h;
        h = Aagg[c * CHANS + chan] * h + Uagg[c * CHANS + chan];
    }
    state_out[chan] = h;
}

// ---------------- scan pass C: replay chunk, write h ----------------
template <int OUT_BF16>
__global__ __launch_bounds__(256) void scan_passC(const u32* __restrict__ GI,
                                                  const float* __restrict__ chunkH0,
                                                  void* __restrict__ outp) {
    int i = blockIdx.x * 256 + threadIdx.x;
    int cp = i & 2047;
    int chunk = i >> 11;
    int b = cp >> 9, h2 = cp & 511;
    size_t rowu = (size_t)(b * T_ + chunk * CLEN) * (H_ / 2) + h2;
    const uint2* p = (const uint2*)GI + rowu;
    const float inv = 1.f / 65535.f;
    int chan = b * 1024 + h2 * 2;
    float h0v = chunkH0[(size_t)chunk * CHANS + chan];
    float h1v = chunkH0[(size_t)chunk * CHANS + chan + 1];
#pragma unroll 4
    for (int t = 0; t < CLEN; ++t) {
        uint2 v = *p;
        float g0 = (float)(v.x & 0xffffu) * inv, in0 = b2f(v.x >> 16);
        float g1 = (float)(v.y & 0xffffu) * inv, in1 = b2f(v.y >> 16);
        h0v = g0 * h0v + in0;
        h1v = g1 * h1v + in1;
        if (OUT_BF16) {
            ((u32*)outp)[rowu] = (u32)f2b(h0v) | ((u32)f2b(h1v) << 16);
        } else {
            ((float2*)outp)[rowu] = make_float2(h0v, h1v);
        }
        p += H_ / 2;
        rowu += H_ / 2;
    }
}

extern "C" void kernel_launch(void* const* d_in, const int* in_sizes, int n_in,
                              void* d_out, int out_size, void* d_ws, size_t ws_size,
                              hipStream_t stream) {
    const float* x = (const float*)d_in[0];
    const float* W0 = (const float*)d_in[1];
    const float* b0 = (const float*)d_in[2];
    const float* W1 = (const float*)d_in[3];
    const float* b1 = (const float*)d_in[4];
    const float* state = (const float*)d_in[5];
    float* out = (float*)d_out;

    char* ws = (char*)d_ws;
    u16* xb = (u16*)ws;                     // 33,554,432 B
    u16* h1b = (u16*)(ws + 33554432);       // 33,554,432 B
    u16* Wt = (u16*)(ws + 67108864);        // 8,388,608 B
    u32* GIb = (u32*)(ws + 75497472);       // 67,108,864 B
    float* Aagg = (float*)(ws + 142606336); // 524,288 B
    float* Uagg = (float*)(ws + 143130624); // 524,288 B
    float* cH0 = (float*)(ws + 143654912);  // 524,288 B

    cvt_x<<<2048, 256, 0, stream>>>(x, xb, M_ * K_ / 8);
    tr_w<<<dim3(32, 64), 256, 0, stream>>>(W0, Wt);
    tr_w<<<dim3(32, 64), 256, 0, stream>>>(W1, Wt + (size_t)N_ * K_);

    for (int l = 0; l < 2; ++l) {
        const u16* Aop = l ? h1b : xb;
        const float* bias = l ? b1 : b0;
        gemm_fused<<<(M_ / BM) * (N_ / BN), 512, 0, stream>>>(
            Aop, Wt + (size_t)l * N_ * K_, bias, GIb, Aagg, Uagg);
        scan_passB<<<CHANS / 256, 256, 0, stream>>>(
            Aagg, Uagg, state + (size_t)l * CHANS, cH0,
            out + (size_t)M_ * H_ + (size_t)l * CHANS);
        if (l == 0)
            scan_passC<1><<<(CHANS * CHUNKS / 2) / 256, 256, 0, stream>>>(GIb, cH0, h1b);
        else
            scan_passC<0><<<(CHANS * CHUNKS / 2) / 256, 256, 0, stream>>>(GIb, cH0, out);
    }
}